// Round 1
// baseline (325.096 us; speedup 1.0000x reference)
//
#include <hip/hip_runtime.h>
#include <hip/hip_bf16.h>

// GraphSAGE: out = normalize( [x, segsum(vals*x[cols], rows)] @ W^T + b )
// N=100000, E=1600000, IN_F=128, OUT_F=128.
//
// Round 5: phase-1 gather pipeline restructured as modulo-4 software pipeline.
// Old loop drained vmcnt(0) every 4-edge group (in-order retire: consuming the
// last gather retired all 12 outstanding loads) -> full loaded round-trip
// exposed per iteration. New: 4 desc banks (lead 4), 2 gather banks (depth 2),
// step = ACC(g); DESC(g+4); GATHER(g+2). Desc lead >= gather depth guarantees
// no desc-wait ever retires an unconsumed gather group.
//
// ws layout:
//   [0    , ~400K)  row_ptr (int[N+1])
//   [448K , 512K)   Wf: fragment-major bf16 W, 4096 x 16B
//   [640K , +25.6M) xb: bf16(x), N x 128 (rows of 16 uint4)

typedef __bf16 bf16x8_t __attribute__((ext_vector_type(8)));
typedef float f32x4_t __attribute__((ext_vector_type(4)));
typedef float f32x2_t __attribute__((ext_vector_type(2)));

__device__ __forceinline__ unsigned int f32_to_bf16(float f) {
    unsigned int u = __float_as_uint(f);
    unsigned int r = u + 0x7fffu + ((u >> 16) & 1u);   // RNE (no NaN inputs)
    return r >> 16;
}
__device__ __forceinline__ unsigned int pack2(float a, float b) {
    return f32_to_bf16(a) | (f32_to_bf16(b) << 16);
}
__device__ __forceinline__ float bflo(unsigned int p) { return __uint_as_float(p << 16); }
__device__ __forceinline__ float bfhi(unsigned int p) { return __uint_as_float(p & 0xffff0000u); }

// --- K0: fused prep: xcast | rowptr | wcast (block-range split) ------------
__global__ void prep_kernel(const float* __restrict__ x, uint4* __restrict__ xb4,
                            const int* __restrict__ rows, int* __restrict__ row_ptr,
                            const float* __restrict__ W, uint4* __restrict__ Wf,
                            int Nn, int Ee, int xcast_blks, int rowptr_blks) {
    int blk = blockIdx.x;
    if (blk < xcast_blks) {
        int i = blk * 256 + threadIdx.x;
        if (i < Nn * 16) {
            const float4* xf = (const float4*)x;
            float4 f0 = xf[(size_t)i * 2];
            float4 f1 = xf[(size_t)i * 2 + 1];
            uint4 o;
            o.x = pack2(f0.x, f0.y); o.y = pack2(f0.z, f0.w);
            o.z = pack2(f1.x, f1.y); o.w = pack2(f1.z, f1.w);
            xb4[i] = o;
        }
    } else if (blk < xcast_blks + rowptr_blks) {
        int n = (blk - xcast_blks) * 256 + threadIdx.x;
        if (n <= Nn) {
            int lo = 0, hi = Ee;
            while (lo < hi) {
                int mid = (lo + hi) >> 1;
                if (rows[mid] < n) lo = mid + 1; else hi = mid;
            }
            row_ptr[n] = lo;
        }
    } else {
        int i = (blk - xcast_blks - rowptr_blks) * 256 + threadIdx.x;  // 0..4095
        int lane = i & 63, ks = (i >> 6) & 7, t = i >> 9;
        int row = t * 16 + (lane & 15);
        int col = ks * 32 + (lane >> 4) * 8;
        const float* p = W + (size_t)row * 256 + col;
        uint4 o;
        o.x = pack2(p[0], p[1]); o.y = pack2(p[2], p[3]);
        o.z = pack2(p[4], p[5]); o.w = pack2(p[6], p[7]);
        Wf[i] = o;
    }
}

// --- K1: fused agg + gemm + normalize --------------------------------------
// block = 256 thr = 4 waves, 16 nodes (grid 6250 exact).
// Phase 1 (agg): wave w, slot h=lane>>4 owns node w*4+h; 16 lanes x 16B
//   cover one 256B xb row. Modulo-4 pipeline: desc banks 0..3 prefetched
//   4 groups ahead; gather banks A/B keep 2 groups of 4 edge-rows in flight
//   across the ACC; fp32 accum -> bf16 to LDS (node-stride 17*16B).
// Phase 2 (gemm): 16 rows, K=256 (self half from global xb, neighbor half
//   from LDS), 8 col-tiles split 2/wave; MFMA 16x16x32 bf16; cross-wave
//   norm reduction through 256B LDS; fused bias+normalize store.
__global__ void fused_kernel(const int* __restrict__ row_ptr,
                             const int* __restrict__ cols,
                             const float* __restrict__ vals,
                             const char* __restrict__ xbB,
                             const bf16x8_t* __restrict__ Wf,
                             const float* __restrict__ b,
                             float* __restrict__ out, int Nn) {
    __shared__ uint4 nbLDS[16 * 17];
    __shared__ float __attribute__((aligned(16))) sqLDS[16][4];

    int lane = threadIdx.x & 63;
    int w    = threadIdx.x >> 6;

    // ---------------- phase 1: aggregate ----------------
    {
        int h = lane >> 4;            // node slot within wave
        int l = lane & 15;            // feature chunk [8l, 8l+8)
        int node = w * 4 + h;         // 0..15
        int n = blockIdx.x * 16 + node;
        int nn = min(n, Nn - 1);
        int start = row_ptr[nn], end = row_ptr[nn + 1];
        if (n >= Nn) end = start;
        unsigned loff = (unsigned)l << 4;

        f32x2_t a0 = {0.f, 0.f}, a1 = {0.f, 0.f}, a2 = {0.f, 0.f}, a3 = {0.f, 0.f};

        // group count (4 edges/group); wave-uniform max over the 4 slots
        int tg = (end - start + 3) >> 2;
        tg = max(tg, __shfl_xor(tg, 16, 64));
        tg = max(tg, __shfl_xor(tg, 32, 64));

        int   c[4][4];     // desc banks: cols
        float v[4][4];     // desc banks: vals (0 beyond segment end)
        uint4 P[2][4];     // gather banks (4 x 16B rows each)

        // Clamped descriptor load: dummy edges re-read cols[end-1] (L1 hit),
        // val forced to 0; max(...,0) guards deg-0 segments at array head.
#define DESC(B, g) {                                                        \
        int e0 = start + ((g) << 2);                                        \
        int q0 = max(min(e0,     end - 1), 0);                              \
        int q1 = max(min(e0 + 1, end - 1), 0);                              \
        int q2 = max(min(e0 + 2, end - 1), 0);                              \
        int q3 = max(min(e0 + 3, end - 1), 0);                              \
        c[B][0] = cols[q0]; c[B][1] = cols[q1];                             \
        c[B][2] = cols[q2]; c[B][3] = cols[q3];                             \
        v[B][0] = (e0     < end) ? vals[q0] : 0.f;                          \
        v[B][1] = (e0 + 1 < end) ? vals[q1] : 0.f;                          \
        v[B][2] = (e0 + 2 < end) ? vals[q2] : 0.f;                          \
        v[B][3] = (e0 + 3 < end) ? vals[q3] : 0.f;                          \
}
#define GATHER(PB, B) {                                                     \
        P[PB][0] = *(const uint4*)(xbB + (((unsigned)c[B][0] << 8) | loff));\
        P[PB][1] = *(const uint4*)(xbB + (((unsigned)c[B][1] << 8) | loff));\
        P[PB][2] = *(const uint4*)(xbB + (((unsigned)c[B][2] << 8) | loff));\
        P[PB][3] = *(const uint4*)(xbB + (((unsigned)c[B][3] << 8) | loff));\
}
#define ACC1(p, V) {                                                        \
        f32x2_t vv = {(V), (V)};                                            \
        f32x2_t t0 = {bflo((p).x), bfhi((p).x)};                            \
        f32x2_t t1 = {bflo((p).y), bfhi((p).y)};                            \
        f32x2_t t2 = {bflo((p).z), bfhi((p).z)};                            \
        f32x2_t t3 = {bflo((p).w), bfhi((p).w)};                            \
        a0 += vv * t0; a1 += vv * t1; a2 += vv * t2; a3 += vv * t3;         \
}
#define ACCG(PB, B) { ACC1(P[PB][0], v[B][0]); ACC1(P[PB][1], v[B][1]);     \
                      ACC1(P[PB][2], v[B][2]); ACC1(P[PB][3], v[B][3]); }

        // prologue: desc banks for groups 0..3, gathers in flight for 0,1
        DESC(0, 0); DESC(1, 1); DESC(2, 2); DESC(3, 3);
        GATHER(0, 0);
        GATHER(1, 1);

        int nit = (tg + 3) >> 2;
        int gb = 0;
        for (int it = 0; it < nit; ++it, gb += 4) {
            // step s: ACC(g=gb+s) waits only its own gather group (vmcnt(12):
            // the other bank + one desc bank stay in flight); DESC refills the
            // bank just consumed (lead 4); GATHER issues g+2 from a desc bank
            // that was loaded 2 steps ago (older than all unconsumed gathers).
            ACCG(0, 0);  DESC(0, gb + 4);  GATHER(0, 2);
            ACCG(1, 1);  DESC(1, gb + 5);  GATHER(1, 3);
            ACCG(0, 2);  DESC(2, gb + 6);  GATHER(0, 0);
            ACCG(1, 3);  DESC(3, gb + 7);  GATHER(1, 1);
        }
#undef DESC
#undef GATHER
#undef ACC1
#undef ACCG

        uint4 o;
        o.x = pack2(a0.x, a0.y); o.y = pack2(a1.x, a1.y);
        o.z = pack2(a2.x, a2.y); o.w = pack2(a3.x, a3.y);
        nbLDS[node * 17 + l] = o;      // bank = (4*node + 4*l) % 32 -> 2-way max
    }
    __syncthreads();

    // ---------------- phase 2: gemm + normalize ----------------
    int m    = lane & 15;
    int quad = lane >> 4;
    int r0   = blockIdx.x * 16;

    int arow = min(r0 + m, Nn - 1);
    const bf16x8_t* Ax = (const bf16x8_t*)(xbB + (size_t)arow * 256);

    bf16x8_t a[8];
#pragma unroll
    for (int ks = 0; ks < 4; ++ks) a[ks] = Ax[ks * 4 + quad];
#pragma unroll
    for (int ks = 0; ks < 4; ++ks)
        a[4 + ks] = *(const bf16x8_t*)&nbLDS[m * 17 + ks * 4 + quad];

    f32x4_t acc[2];
    float bc[2];
#pragma unroll
    for (int j = 0; j < 2; ++j) {
        int t = w * 2 + j;
        acc[j] = (f32x4_t){0.f, 0.f, 0.f, 0.f};
        bc[j]  = b[t * 16 + m];
#pragma unroll
        for (int ks = 0; ks < 8; ++ks) {
            acc[j] = __builtin_amdgcn_mfma_f32_16x16x32_bf16(
                a[ks], Wf[(t * 8 + ks) * 64 + lane], acc[j], 0, 0, 0);
        }
    }

    // per-row sum of squares: lane holds rows quad*4+r, cols (w*2+j)*16+m
    float sq[4] = {0.f, 0.f, 0.f, 0.f};
#pragma unroll
    for (int j = 0; j < 2; ++j)
#pragma unroll
        for (int r = 0; r < 4; ++r) {
            float u = acc[j][r] + bc[j];
            sq[r] += u * u;
        }
#pragma unroll
    for (int off = 1; off <= 8; off <<= 1) {
#pragma unroll
        for (int r = 0; r < 4; ++r) sq[r] += __shfl_xor(sq[r], off, 64);
    }
    if (m == 0) {
#pragma unroll
        for (int r = 0; r < 4; ++r) sqLDS[quad * 4 + r][w] = sq[r];
    }
    __syncthreads();

    float scale[4];
#pragma unroll
    for (int r = 0; r < 4; ++r) {
        const float4 q4 = *(const float4*)sqLDS[quad * 4 + r];
        float tot = q4.x + q4.y + q4.z + q4.w;
        scale[r] = 1.f / fmaxf(sqrtf(tot), 1e-12f);
    }

#pragma unroll
    for (int r = 0; r < 4; ++r) {
        int row = r0 + quad * 4 + r;
        if (row < Nn) {
            float* orow = out + (size_t)row * 128;
#pragma unroll
            for (int j = 0; j < 2; ++j) {
                int t = w * 2 + j;
                orow[t * 16 + m] = (acc[j][r] + bc[j]) * scale[r];
            }
        }
    }
}

extern "C" void kernel_launch(void* const* d_in, const int* in_sizes, int n_in,
                              void* d_out, int out_size, void* d_ws, size_t ws_size,
                              hipStream_t stream) {
    const float* x    = (const float*)d_in[0];
    const int*   rows = (const int*)  d_in[1];
    const int*   cols = (const int*)  d_in[2];
    const float* vals = (const float*)d_in[3];
    const float* W    = (const float*)d_in[4];
    const float* b    = (const float*)d_in[5];
    float*       out  = (float*)d_out;

    const int Nn = in_sizes[0] / 128;    // 100000
    const int Ee = in_sizes[1];          // 1600000

    char*  ws      = (char*)d_ws;
    int*   row_ptr = (int*)ws;
    uint4* Wf      = (uint4*)(ws + 448 * 1024);
    uint4* xb      = (uint4*)(ws + 640 * 1024);

    const int xcast_blks  = (Nn * 16 + 255) / 256;   // 6250
    const int rowptr_blks = (Nn + 1 + 255) / 256;    // 391
    const int wcast_blks  = 16;

    prep_kernel<<<xcast_blks + rowptr_blks + wcast_blks, 256, 0, stream>>>(
        x, xb, rows, row_ptr, W, Wf, Nn, Ee, xcast_blks, rowptr_blks);
    fused_kernel<<<(Nn + 15) / 16, 256, 0, stream>>>(
        row_ptr, cols, vals, (const char*)xb,
        (const bf16x8_t*)Wf, b, out, Nn);
}

// Round 2
// 193.210 us; speedup vs baseline: 1.6826x; 1.6826x over previous
//
#include <hip/hip_runtime.h>
#include <hip/hip_bf16.h>

// GraphSAGE: out = normalize( [x, segsum(vals*x[cols], rows)] @ W^T + b )
// N=100000, E=1600000, IN_F=128, OUT_F=128.
//
// Round 6: phase-1 gather MLP via global_load_lds ring (depth 4, zero VGPR
// payload) + block-staged LDS descriptors (lgkmcnt path, so counted
// vmcnt(3) waits only ever count gathers). Round-5 lesson: register-resident
// desc/payload banks spilled to scratch (WRITE_SIZE 50->409 MB); descriptors
// and payloads now both live in LDS.
//
// ws layout:
//   [0    , ~400K)  row_ptr (int[N+1])
//   [448K , 512K)   Wf: fragment-major bf16 W, 4096 x 16B
//   [640K , +25.6M) xb: bf16(x), N x 128 (rows of 16 uint4)

typedef __bf16 bf16x8_t __attribute__((ext_vector_type(8)));
typedef float f32x4_t __attribute__((ext_vector_type(4)));
typedef float f32x2_t __attribute__((ext_vector_type(2)));

#define DESC_CAP 768   // max staged edges per block (mean 256, ~32 sigma)
#define RING_D   4     // gather groups in flight per wave

__device__ __forceinline__ unsigned int f32_to_bf16(float f) {
    unsigned int u = __float_as_uint(f);
    unsigned int r = u + 0x7fffu + ((u >> 16) & 1u);   // RNE (no NaN inputs)
    return r >> 16;
}
__device__ __forceinline__ unsigned int pack2(float a, float b) {
    return f32_to_bf16(a) | (f32_to_bf16(b) << 16);
}
__device__ __forceinline__ float bflo(unsigned int p) { return __uint_as_float(p << 16); }
__device__ __forceinline__ float bfhi(unsigned int p) { return __uint_as_float(p & 0xffff0000u); }

// CK-style global->LDS direct load (16B per lane; global addr per-lane,
// LDS dest wave-uniform base + lane*16). uintptr casts produce the AS1/AS3
// pointers the builtin requires (LDS flat-address low 32 bits == LDS offset).
__device__ __forceinline__ void gload_lds16(const char* g, void* l) {
    auto gp = reinterpret_cast<__attribute__((address_space(1))) unsigned int*>(
        reinterpret_cast<uintptr_t>(g));
    auto lp = reinterpret_cast<__attribute__((address_space(3))) unsigned int*>(
        reinterpret_cast<uintptr_t>(l));
    __builtin_amdgcn_global_load_lds(gp, lp, 16, 0, 0);
}

// --- K0: fused prep: xcast | rowptr | wcast (block-range split) ------------
__global__ void prep_kernel(const float* __restrict__ x, uint4* __restrict__ xb4,
                            const int* __restrict__ rows, int* __restrict__ row_ptr,
                            const float* __restrict__ W, uint4* __restrict__ Wf,
                            int Nn, int Ee, int xcast_blks, int rowptr_blks) {
    int blk = blockIdx.x;
    if (blk < xcast_blks) {
        int i = blk * 256 + threadIdx.x;
        if (i < Nn * 16) {
            const float4* xf = (const float4*)x;
            float4 f0 = xf[(size_t)i * 2];
            float4 f1 = xf[(size_t)i * 2 + 1];
            uint4 o;
            o.x = pack2(f0.x, f0.y); o.y = pack2(f0.z, f0.w);
            o.z = pack2(f1.x, f1.y); o.w = pack2(f1.z, f1.w);
            xb4[i] = o;
        }
    } else if (blk < xcast_blks + rowptr_blks) {
        int n = (blk - xcast_blks) * 256 + threadIdx.x;
        if (n <= Nn) {
            int lo = 0, hi = Ee;
            while (lo < hi) {
                int mid = (lo + hi) >> 1;
                if (rows[mid] < n) lo = mid + 1; else hi = mid;
            }
            row_ptr[n] = lo;
        }
    } else {
        int i = (blk - xcast_blks - rowptr_blks) * 256 + threadIdx.x;  // 0..4095
        int lane = i & 63, ks = (i >> 6) & 7, t = i >> 9;
        int row = t * 16 + (lane & 15);
        int col = ks * 32 + (lane >> 4) * 8;
        const float* p = W + (size_t)row * 256 + col;
        uint4 o;
        o.x = pack2(p[0], p[1]); o.y = pack2(p[2], p[3]);
        o.z = pack2(p[4], p[5]); o.w = pack2(p[6], p[7]);
        Wf[i] = o;
    }
}

// --- K1: fused agg + gemm + normalize --------------------------------------
// block = 256 thr = 4 waves, 16 nodes (grid 6250 exact).
// Phase 1 (agg): wave w, slot h=lane>>4 owns node w*4+h; 16 lanes x 16B
//   cover one 256B xb row. Descriptors (cols/vals) staged block-wide in LDS.
//   Gather ring: RING_D global_load_lds instrs in flight per wave (1 KB each:
//   one edge-row per slot). Steady state per step: vmcnt(3) -> ds_read P/desc
//   -> lgkmcnt(0) -> reissue slot -> FMA. Only gathers occupy vmcnt.
// Phase 2 (gemm): 16 rows, K=256 (self half from global xb, neighbor half
//   from LDS), 8 col-tiles split 2/wave; MFMA 16x16x32 bf16; cross-wave
//   norm reduction through 256B LDS; fused bias+normalize store.
__global__ void fused_kernel(const int* __restrict__ row_ptr,
                             const int* __restrict__ cols,
                             const float* __restrict__ vals,
                             const char* __restrict__ xbB,
                             const bf16x8_t* __restrict__ Wf,
                             const float* __restrict__ b,
                             float* __restrict__ out, int Nn) {
    __shared__ uint4 ring[4][RING_D][64];                 // 16 KB gather ring
    __shared__ int   cLDS[DESC_CAP];                      // 3 KB
    __shared__ float vLDS[DESC_CAP];                      // 3 KB
    __shared__ uint4 nbLDS[16 * 17];                      // 4.25 KB
    __shared__ float __attribute__((aligned(16))) sqLDS[16][4];

    int lane = threadIdx.x & 63;
    int w    = threadIdx.x >> 6;
    int r0   = blockIdx.x * 16;

    int eLo = row_ptr[r0];
    int eHi = row_ptr[min(r0 + 16, Nn)];
    int cnt = eHi - eLo;
    bool big = cnt > DESC_CAP;     // block-uniform; ~never on this input

    if (!big) {
        for (int i = threadIdx.x; i < cnt; i += 256) {
            cLDS[i] = cols[eLo + i];
            vLDS[i] = vals[eLo + i];
        }
        if (threadIdx.x == 0 && cnt == 0) { cLDS[0] = 0; vLDS[0] = 0.f; }
    }
    __syncthreads();

    // ---------------- phase 1: aggregate ----------------
    {
        int h = lane >> 4;            // node slot within wave
        int l = lane & 15;            // feature chunk [8l, 8l+8)
        int node = w * 4 + h;         // 0..15
        int n = r0 + node;
        int nn = min(n, Nn - 1);
        int start = row_ptr[nn], end = row_ptr[nn + 1];
        if (n >= Nn) end = start;
        unsigned loff = (unsigned)l << 4;

        f32x2_t a0 = {0.f, 0.f}, a1 = {0.f, 0.f}, a2 = {0.f, 0.f}, a3 = {0.f, 0.f};

#define ACC1(p, V) {                                                        \
        f32x2_t vv2 = {(V), (V)};                                           \
        f32x2_t t0 = {bflo((p).x), bfhi((p).x)};                            \
        f32x2_t t1 = {bflo((p).y), bfhi((p).y)};                            \
        f32x2_t t2 = {bflo((p).z), bfhi((p).z)};                            \
        f32x2_t t3 = {bflo((p).w), bfhi((p).w)};                            \
        a0 += vv2 * t0; a1 += vv2 * t1; a2 += vv2 * t2; a3 += vv2 * t3;     \
}

        if (!big) {
            int deg   = end - start;          // per-slot degree
            int degm1 = deg - 1;
            int soff  = start - eLo;          // slot's local desc offset
            int tgw   = deg;                  // wave-uniform step count
            tgw = max(tgw, __shfl_xor(tgw, 16, 64));
            tgw = max(tgw, __shfl_xor(tgw, 32, 64));

            // prologue: fill the ring (clamped dummies re-read last valid row)
#pragma unroll
            for (int s = 0; s < RING_D; ++s) {
                int idx = max(soff + min(s, degm1), 0);
                int c = cLDS[idx];
                gload_lds16(xbB + (((unsigned)c << 8) | loff), &ring[w][s][0]);
            }

            for (int g = 0; g < tgw; ++g) {
                // oldest gather (group g) has landed; 3 stay in flight
                asm volatile("s_waitcnt vmcnt(3)" ::: "memory");
                uint4 P = ring[w][g & (RING_D - 1)][lane];
                int idxN = max(soff + min(g + RING_D, degm1), 0);
                int cN   = cLDS[idxN];
                int idxV = max(soff + min(g, degm1), 0);
                float vv = vLDS[idxV];
                if (g >= deg) vv = 0.f;       // dummy step for short slots
                // ring slot g%D fully read + desc in regs before reissue
                asm volatile("s_waitcnt lgkmcnt(0)" ::: "memory");
                gload_lds16(xbB + (((unsigned)cN << 8) | loff),
                            &ring[w][g & (RING_D - 1)][0]);
                ACC1(P, vv);
            }
            // tail gathers (dummies) drain at the barrier below
        } else {
            // oversized block: proven register-pipelined fallback (Round 4)
#define EDGE4B(E, C0, C1, C2, C3, V0, V1, V2, V3)                               \
            {                                                                   \
                int q0 = min((E), end - 1),     q1 = min((E) + 1, end - 1);     \
                int q2 = min((E) + 2, end - 1), q3 = min((E) + 3, end - 1);     \
                C0 = cols[q0]; C1 = cols[q1]; C2 = cols[q2]; C3 = cols[q3];     \
                V0 = ((E)     < end) ? vals[q0] : 0.f;                          \
                V1 = ((E) + 1 < end) ? vals[q1] : 0.f;                          \
                V2 = ((E) + 2 < end) ? vals[q2] : 0.f;                          \
                V3 = ((E) + 3 < end) ? vals[q3] : 0.f;                          \
            }
            int e = start;
            int c0 = 0, c1 = 0, c2 = 0, c3 = 0;
            float v0 = 0.f, v1 = 0.f, v2 = 0.f, v3 = 0.f;
            if (e < end) EDGE4B(e, c0, c1, c2, c3, v0, v1, v2, v3);
            while (e < end) {
                int en = e + 4;
                int d0 = 0, d1 = 0, d2 = 0, d3 = 0;
                float w0 = 0.f, w1 = 0.f, w2 = 0.f, w3 = 0.f;
                if (en < end) EDGE4B(en, d0, d1, d2, d3, w0, w1, w2, w3);
                uint4 p0 = *(const uint4*)(xbB + (((unsigned)c0 << 8) | loff));
                uint4 p1 = *(const uint4*)(xbB + (((unsigned)c1 << 8) | loff));
                uint4 p2 = *(const uint4*)(xbB + (((unsigned)c2 << 8) | loff));
                uint4 p3 = *(const uint4*)(xbB + (((unsigned)c3 << 8) | loff));
                ACC1(p0, v0); ACC1(p1, v1); ACC1(p2, v2); ACC1(p3, v3);
                c0 = d0; c1 = d1; c2 = d2; c3 = d3;
                v0 = w0; v1 = w1; v2 = w2; v3 = w3;
                e = en;
            }
#undef EDGE4B
        }
#undef ACC1

        uint4 o;
        o.x = pack2(a0.x, a0.y); o.y = pack2(a1.x, a1.y);
        o.z = pack2(a2.x, a2.y); o.w = pack2(a3.x, a3.y);
        nbLDS[node * 17 + l] = o;      // bank = (4*node + 4*l) % 32 -> 2-way max
    }
    __syncthreads();

    // ---------------- phase 2: gemm + normalize ----------------
    int m    = lane & 15;
    int quad = lane >> 4;

    int arow = min(r0 + m, Nn - 1);
    const bf16x8_t* Ax = (const bf16x8_t*)(xbB + (size_t)arow * 256);

    bf16x8_t a[8];
#pragma unroll
    for (int ks = 0; ks < 4; ++ks) a[ks] = Ax[ks * 4 + quad];
#pragma unroll
    for (int ks = 0; ks < 4; ++ks)
        a[4 + ks] = *(const bf16x8_t*)&nbLDS[m * 17 + ks * 4 + quad];

    f32x4_t acc[2];
    float bc[2];
#pragma unroll
    for (int j = 0; j < 2; ++j) {
        int t = w * 2 + j;
        acc[j] = (f32x4_t){0.f, 0.f, 0.f, 0.f};
        bc[j]  = b[t * 16 + m];
#pragma unroll
        for (int ks = 0; ks < 8; ++ks) {
            acc[j] = __builtin_amdgcn_mfma_f32_16x16x32_bf16(
                a[ks], Wf[(t * 8 + ks) * 64 + lane], acc[j], 0, 0, 0);
        }
    }

    // per-row sum of squares: lane holds rows quad*4+r, cols (w*2+j)*16+m
    float sq[4] = {0.f, 0.f, 0.f, 0.f};
#pragma unroll
    for (int j = 0; j < 2; ++j)
#pragma unroll
        for (int r = 0; r < 4; ++r) {
            float u = acc[j][r] + bc[j];
            sq[r] += u * u;
        }
#pragma unroll
    for (int off = 1; off <= 8; off <<= 1) {
#pragma unroll
        for (int r = 0; r < 4; ++r) sq[r] += __shfl_xor(sq[r], off, 64);
    }
    if (m == 0) {
#pragma unroll
        for (int r = 0; r < 4; ++r) sqLDS[quad * 4 + r][w] = sq[r];
    }
    __syncthreads();

    float scale[4];
#pragma unroll
    for (int r = 0; r < 4; ++r) {
        const float4 q4 = *(const float4*)sqLDS[quad * 4 + r];
        float tot = q4.x + q4.y + q4.z + q4.w;
        scale[r] = 1.f / fmaxf(sqrtf(tot), 1e-12f);
    }

#pragma unroll
    for (int r = 0; r < 4; ++r) {
        int row = r0 + quad * 4 + r;
        if (row < Nn) {
            float* orow = out + (size_t)row * 128;
#pragma unroll
            for (int j = 0; j < 2; ++j) {
                int t = w * 2 + j;
                orow[t * 16 + m] = (acc[j][r] + bc[j]) * scale[r];
            }
        }
    }
}

extern "C" void kernel_launch(void* const* d_in, const int* in_sizes, int n_in,
                              void* d_out, int out_size, void* d_ws, size_t ws_size,
                              hipStream_t stream) {
    const float* x    = (const float*)d_in[0];
    const int*   rows = (const int*)  d_in[1];
    const int*   cols = (const int*)  d_in[2];
    const float* vals = (const float*)d_in[3];
    const float* W    = (const float*)d_in[4];
    const float* b    = (const float*)d_in[5];
    float*       out  = (float*)d_out;

    const int Nn = in_sizes[0] / 128;    // 100000
    const int Ee = in_sizes[1];          // 1600000

    char*  ws      = (char*)d_ws;
    int*   row_ptr = (int*)ws;
    uint4* Wf      = (uint4*)(ws + 448 * 1024);
    uint4* xb      = (uint4*)(ws + 640 * 1024);

    const int xcast_blks  = (Nn * 16 + 255) / 256;   // 6250
    const int rowptr_blks = (Nn + 1 + 255) / 256;    // 391
    const int wcast_blks  = 16;

    prep_kernel<<<xcast_blks + rowptr_blks + wcast_blks, 256, 0, stream>>>(
        x, xb, rows, row_ptr, W, Wf, Nn, Ee, xcast_blks, rowptr_blks);
    fused_kernel<<<(Nn + 15) / 16, 256, 0, stream>>>(
        row_ptr, cols, vals, (const char*)xb,
        (const bf16x8_t*)Wf, b, out, Nn);
}

// Round 3
// 191.806 us; speedup vs baseline: 1.6949x; 1.0073x over previous
//
#include <hip/hip_runtime.h>
#include <hip/hip_bf16.h>

// GraphSAGE: out = normalize( [x, segsum(vals*x[cols], rows)] @ W^T + b )
// N=100000, E=1600000, IN_F=128, OUT_F=128.
//
// Round 7: concurrency + anti-pollution pass on the Round-6 structure.
//  - DESC_CAP 768->512: LDS 27->24.9 KB -> 6 blocks/CU (occ 47->~72%),
//    +60% in-flight gather bytes (tests concurrency-vs-service-cap).
//  - Non-temporal stores for out / xb, NT loads for cols/vals/x streams:
//    stop 50 MB of write-allocate pollution of the 4 MB per-XCD L2 that
//    the gather depends on for its ~2x reuse.
//  - Gather loads remain cacheable (they carry all reuse). Numerics identical.
//
// ws layout:
//   [0    , ~400K)  row_ptr (int[N+1])
//   [448K , 512K)   Wf: fragment-major bf16 W, 4096 x 16B
//   [640K , +25.6M) xb: bf16(x), N x 128 (rows of 16 uint4)

typedef __bf16 bf16x8_t __attribute__((ext_vector_type(8)));
typedef float f32x4_t __attribute__((ext_vector_type(4)));
typedef float f32x2_t __attribute__((ext_vector_type(2)));
typedef unsigned int u32x4_t __attribute__((ext_vector_type(4)));

#define DESC_CAP 512   // max staged edges per block (mean 256, std 16 -> 16 sigma)
#define RING_D   4     // gather groups in flight per wave

__device__ __forceinline__ unsigned int f32_to_bf16(float f) {
    unsigned int u = __float_as_uint(f);
    unsigned int r = u + 0x7fffu + ((u >> 16) & 1u);   // RNE (no NaN inputs)
    return r >> 16;
}
__device__ __forceinline__ unsigned int pack2(float a, float b) {
    return f32_to_bf16(a) | (f32_to_bf16(b) << 16);
}
__device__ __forceinline__ float bflo(unsigned int p) { return __uint_as_float(p << 16); }
__device__ __forceinline__ float bfhi(unsigned int p) { return __uint_as_float(p & 0xffff0000u); }

// CK-style global->LDS direct load (16B per lane; global addr per-lane,
// LDS dest wave-uniform base + lane*16).
__device__ __forceinline__ void gload_lds16(const char* g, void* l) {
    auto gp = reinterpret_cast<__attribute__((address_space(1))) unsigned int*>(
        reinterpret_cast<uintptr_t>(g));
    auto lp = reinterpret_cast<__attribute__((address_space(3))) unsigned int*>(
        reinterpret_cast<uintptr_t>(l));
    __builtin_amdgcn_global_load_lds(gp, lp, 16, 0, 0);
}

// --- K0: fused prep: xcast | rowptr | wcast (block-range split) ------------
__global__ void prep_kernel(const float* __restrict__ x, uint4* __restrict__ xb4,
                            const int* __restrict__ rows, int* __restrict__ row_ptr,
                            const float* __restrict__ W, uint4* __restrict__ Wf,
                            int Nn, int Ee, int xcast_blks, int rowptr_blks) {
    int blk = blockIdx.x;
    if (blk < xcast_blks) {
        int i = blk * 256 + threadIdx.x;
        if (i < Nn * 16) {
            const f32x4_t* xf = (const f32x4_t*)x;           // read-once: NT
            f32x4_t f0 = __builtin_nontemporal_load(&xf[(size_t)i * 2]);
            f32x4_t f1 = __builtin_nontemporal_load(&xf[(size_t)i * 2 + 1]);
            u32x4_t o;
            o.x = pack2(f0.x, f0.y); o.y = pack2(f0.z, f0.w);
            o.z = pack2(f1.x, f1.y); o.w = pack2(f1.z, f1.w);
            // write-once (readers are on other XCDs; serve them from L3):
            __builtin_nontemporal_store(o, (u32x4_t*)&xb4[i]);
        }
    } else if (blk < xcast_blks + rowptr_blks) {
        int n = (blk - xcast_blks) * 256 + threadIdx.x;
        if (n <= Nn) {
            int lo = 0, hi = Ee;
            while (lo < hi) {
                int mid = (lo + hi) >> 1;
                if (rows[mid] < n) lo = mid + 1; else hi = mid;
            }
            row_ptr[n] = lo;
        }
    } else {
        int i = (blk - xcast_blks - rowptr_blks) * 256 + threadIdx.x;  // 0..4095
        int lane = i & 63, ks = (i >> 6) & 7, t = i >> 9;
        int row = t * 16 + (lane & 15);
        int col = ks * 32 + (lane >> 4) * 8;
        const float* p = W + (size_t)row * 256 + col;
        uint4 o;
        o.x = pack2(p[0], p[1]); o.y = pack2(p[2], p[3]);
        o.z = pack2(p[4], p[5]); o.w = pack2(p[6], p[7]);
        Wf[i] = o;                       // hot: every block re-reads -> cacheable
    }
}

// --- K1: fused agg + gemm + normalize --------------------------------------
// block = 256 thr = 4 waves, 16 nodes (grid 6250 exact).
// Phase 1 (agg): wave w, slot h=lane>>4 owns node w*4+h; 16 lanes x 16B
//   cover one 256B xb row. Descriptors (cols/vals) staged block-wide in LDS.
//   Gather ring: RING_D global_load_lds in flight per wave (1 KB each).
//   Steady state per step: vmcnt(3) -> ds_read P/desc -> lgkmcnt(0) ->
//   reissue slot -> FMA. Only gathers occupy vmcnt.
// Phase 2 (gemm): 16 rows, K=256 (self half from global xb, neighbor half
//   from LDS), 8 col-tiles split 2/wave; MFMA 16x16x32 bf16; cross-wave
//   norm reduction through 256B LDS; fused bias+normalize NT store.
__global__ void __launch_bounds__(256, 6)
fused_kernel(const int* __restrict__ row_ptr,
             const int* __restrict__ cols,
             const float* __restrict__ vals,
             const char* __restrict__ xbB,
             const bf16x8_t* __restrict__ Wf,
             const float* __restrict__ b,
             float* __restrict__ out, int Nn) {
    __shared__ uint4 ring[4][RING_D][64];                 // 16 KB gather ring
    __shared__ int   cLDS[DESC_CAP];                      // 2 KB
    __shared__ float vLDS[DESC_CAP];                      // 2 KB
    __shared__ uint4 nbLDS[16 * 17];                      // 4.25 KB
    __shared__ float __attribute__((aligned(16))) sqLDS[16][4];

    int lane = threadIdx.x & 63;
    int w    = threadIdx.x >> 6;
    int r0   = blockIdx.x * 16;

    int eLo = row_ptr[r0];
    int eHi = row_ptr[min(r0 + 16, Nn)];
    int cnt = eHi - eLo;
    bool big = cnt > DESC_CAP;     // block-uniform; ~never on this input

    if (!big) {
        for (int i = threadIdx.x; i < cnt; i += 256) {
            cLDS[i] = __builtin_nontemporal_load(&cols[eLo + i]);
            vLDS[i] = __builtin_nontemporal_load(&vals[eLo + i]);
        }
        if (threadIdx.x == 0 && cnt == 0) { cLDS[0] = 0; vLDS[0] = 0.f; }
    }
    __syncthreads();

    // ---------------- phase 1: aggregate ----------------
    {
        int h = lane >> 4;            // node slot within wave
        int l = lane & 15;            // feature chunk [8l, 8l+8)
        int node = w * 4 + h;         // 0..15
        int n = r0 + node;
        int nn = min(n, Nn - 1);
        int start = row_ptr[nn], end = row_ptr[nn + 1];
        if (n >= Nn) end = start;
        unsigned loff = (unsigned)l << 4;

        f32x2_t a0 = {0.f, 0.f}, a1 = {0.f, 0.f}, a2 = {0.f, 0.f}, a3 = {0.f, 0.f};

#define ACC1(p, V) {                                                        \
        f32x2_t vv2 = {(V), (V)};                                           \
        f32x2_t t0 = {bflo((p).x), bfhi((p).x)};                            \
        f32x2_t t1 = {bflo((p).y), bfhi((p).y)};                            \
        f32x2_t t2 = {bflo((p).z), bfhi((p).z)};                            \
        f32x2_t t3 = {bflo((p).w), bfhi((p).w)};                            \
        a0 += vv2 * t0; a1 += vv2 * t1; a2 += vv2 * t2; a3 += vv2 * t3;     \
}

        if (!big) {
            int deg   = end - start;          // per-slot degree
            int degm1 = deg - 1;
            int soff  = start - eLo;          // slot's local desc offset
            int tgw   = deg;                  // wave-uniform step count
            tgw = max(tgw, __shfl_xor(tgw, 16, 64));
            tgw = max(tgw, __shfl_xor(tgw, 32, 64));

            // prologue: fill the ring (clamped dummies re-read last valid row)
#pragma unroll
            for (int s = 0; s < RING_D; ++s) {
                int idx = max(soff + min(s, degm1), 0);
                int c = cLDS[idx];
                gload_lds16(xbB + (((unsigned)c << 8) | loff), &ring[w][s][0]);
            }

            for (int g = 0; g < tgw; ++g) {
                // oldest gather (group g) has landed; 3 stay in flight
                asm volatile("s_waitcnt vmcnt(3)" ::: "memory");
                uint4 P = ring[w][g & (RING_D - 1)][lane];
                int idxN = max(soff + min(g + RING_D, degm1), 0);
                int cN   = cLDS[idxN];
                int idxV = max(soff + min(g, degm1), 0);
                float vv = vLDS[idxV];
                if (g >= deg) vv = 0.f;       // dummy step for short slots
                // ring slot g%D fully read + desc in regs before reissue
                asm volatile("s_waitcnt lgkmcnt(0)" ::: "memory");
                gload_lds16(xbB + (((unsigned)cN << 8) | loff),
                            &ring[w][g & (RING_D - 1)][0]);
                ACC1(P, vv);
            }
            // tail gathers (dummies) drain at the barrier below
        } else {
            // oversized block: proven register-pipelined fallback (Round 4)
#define EDGE4B(E, C0, C1, C2, C3, V0, V1, V2, V3)                               \
            {                                                                   \
                int q0 = min((E), end - 1),     q1 = min((E) + 1, end - 1);     \
                int q2 = min((E) + 2, end - 1), q3 = min((E) + 3, end - 1);     \
                C0 = cols[q0]; C1 = cols[q1]; C2 = cols[q2]; C3 = cols[q3];     \
                V0 = ((E)     < end) ? vals[q0] : 0.f;                          \
                V1 = ((E) + 1 < end) ? vals[q1] : 0.f;                          \
                V2 = ((E) + 2 < end) ? vals[q2] : 0.f;                          \
                V3 = ((E) + 3 < end) ? vals[q3] : 0.f;                          \
            }
            int e = start;
            int c0 = 0, c1 = 0, c2 = 0, c3 = 0;
            float v0 = 0.f, v1 = 0.f, v2 = 0.f, v3 = 0.f;
            if (e < end) EDGE4B(e, c0, c1, c2, c3, v0, v1, v2, v3);
            while (e < end) {
                int en = e + 4;
                int d0 = 0, d1 = 0, d2 = 0, d3 = 0;
                float w0 = 0.f, w1 = 0.f, w2 = 0.f, w3 = 0.f;
                if (en < end) EDGE4B(en, d0, d1, d2, d3, w0, w1, w2, w3);
                uint4 p0 = *(const uint4*)(xbB + (((unsigned)c0 << 8) | loff));
                uint4 p1 = *(const uint4*)(xbB + (((unsigned)c1 << 8) | loff));
                uint4 p2 = *(const uint4*)(xbB + (((unsigned)c2 << 8) | loff));
                uint4 p3 = *(const uint4*)(xbB + (((unsigned)c3 << 8) | loff));
                ACC1(p0, v0); ACC1(p1, v1); ACC1(p2, v2); ACC1(p3, v3);
                c0 = d0; c1 = d1; c2 = d2; c3 = d3;
                v0 = w0; v1 = w1; v2 = w2; v3 = w3;
                e = en;
            }
#undef EDGE4B
        }
#undef ACC1

        uint4 o;
        o.x = pack2(a0.x, a0.y); o.y = pack2(a1.x, a1.y);
        o.z = pack2(a2.x, a2.y); o.w = pack2(a3.x, a3.y);
        nbLDS[node * 17 + l] = o;      // bank = (4*node + 4*l) % 32 -> 2-way max
    }
    __syncthreads();

    // ---------------- phase 2: gemm + normalize ----------------
    int m    = lane & 15;
    int quad = lane >> 4;

    int arow = min(r0 + m, Nn - 1);
    const bf16x8_t* Ax = (const bf16x8_t*)(xbB + (size_t)arow * 256);

    bf16x8_t a[8];
#pragma unroll
    for (int ks = 0; ks < 4; ++ks) a[ks] = Ax[ks * 4 + quad];
#pragma unroll
    for (int ks = 0; ks < 4; ++ks)
        a[4 + ks] = *(const bf16x8_t*)&nbLDS[m * 17 + ks * 4 + quad];

    f32x4_t acc[2];
    float bc[2];
#pragma unroll
    for (int j = 0; j < 2; ++j) {
        int t = w * 2 + j;
        acc[j] = (f32x4_t){0.f, 0.f, 0.f, 0.f};
        bc[j]  = b[t * 16 + m];
#pragma unroll
        for (int ks = 0; ks < 8; ++ks) {
            acc[j] = __builtin_amdgcn_mfma_f32_16x16x32_bf16(
                a[ks], Wf[(t * 8 + ks) * 64 + lane], acc[j], 0, 0, 0);
        }
    }

    // per-row sum of squares: lane holds rows quad*4+r, cols (w*2+j)*16+m
    float sq[4] = {0.f, 0.f, 0.f, 0.f};
#pragma unroll
    for (int j = 0; j < 2; ++j)
#pragma unroll
        for (int r = 0; r < 4; ++r) {
            float u = acc[j][r] + bc[j];
            sq[r] += u * u;
        }
#pragma unroll
    for (int off = 1; off <= 8; off <<= 1) {
#pragma unroll
        for (int r = 0; r < 4; ++r) sq[r] += __shfl_xor(sq[r], off, 64);
    }
    if (m == 0) {
#pragma unroll
        for (int r = 0; r < 4; ++r) sqLDS[quad * 4 + r][w] = sq[r];
    }
    __syncthreads();

    float scale[4];
#pragma unroll
    for (int r = 0; r < 4; ++r) {
        const float4 q4 = *(const float4*)sqLDS[quad * 4 + r];
        float tot = q4.x + q4.y + q4.z + q4.w;
        scale[r] = 1.f / fmaxf(sqrtf(tot), 1e-12f);
    }

#pragma unroll
    for (int r = 0; r < 4; ++r) {
        int row = r0 + quad * 4 + r;
        if (row < Nn) {
            float* orow = out + (size_t)row * 128;
#pragma unroll
            for (int j = 0; j < 2; ++j) {
                int t = w * 2 + j;
                __builtin_nontemporal_store((acc[j][r] + bc[j]) * scale[r],
                                            &orow[t * 16 + m]);
            }
        }
    }
}

extern "C" void kernel_launch(void* const* d_in, const int* in_sizes, int n_in,
                              void* d_out, int out_size, void* d_ws, size_t ws_size,
                              hipStream_t stream) {
    const float* x    = (const float*)d_in[0];
    const int*   rows = (const int*)  d_in[1];
    const int*   cols = (const int*)  d_in[2];
    const float* vals = (const float*)d_in[3];
    const float* W    = (const float*)d_in[4];
    const float* b    = (const float*)d_in[5];
    float*       out  = (float*)d_out;

    const int Nn = in_sizes[0] / 128;    // 100000
    const int Ee = in_sizes[1];          // 1600000

    char*  ws      = (char*)d_ws;
    int*   row_ptr = (int*)ws;
    uint4* Wf      = (uint4*)(ws + 448 * 1024);
    uint4* xb      = (uint4*)(ws + 640 * 1024);

    const int xcast_blks  = (Nn * 16 + 255) / 256;   // 6250
    const int rowptr_blks = (Nn + 1 + 255) / 256;    // 391
    const int wcast_blks  = 16;

    prep_kernel<<<xcast_blks + rowptr_blks + wcast_blks, 256, 0, stream>>>(
        x, xb, rows, row_ptr, W, Wf, Nn, Ee, xcast_blks, rowptr_blks);
    fused_kernel<<<(Nn + 15) / 16, 256, 0, stream>>>(
        row_ptr, cols, vals, (const char*)xb,
        (const bf16x8_t*)Wf, b, out, Nn);
}